// Round 6
// baseline (228.966 us; speedup 1.0000x reference)
//
#include <hip/hip_runtime.h>
#include <stdint.h>

#define B_ 8
#define H_ 128
#define W_ 128
#define D_ 128
#define N_ (H_*W_)
#define M_ (B_*N_)   // 131072 rows total

typedef __attribute__((ext_vector_type(8))) short short8;
typedef __attribute__((ext_vector_type(4))) float floatx4;

typedef const __attribute__((address_space(1))) void* gas_t;
typedef __attribute__((address_space(3))) void* las_t;

__device__ inline unsigned short f2bf(float f){
  union { float f; unsigned int i; } c; c.f = f;
  unsigned int x = c.i;
  x += 0x7FFF + ((x >> 16) & 1);   // RNE
  return (unsigned short)(x >> 16);
}
__device__ inline float bflo(unsigned int u){
  union { unsigned int i; float f; } c; c.i = u << 16; return c.f;
}
__device__ inline float bfhi(unsigned int u){
  union { unsigned int i; float f; } c; c.i = u & 0xFFFF0000u; return c.f;
}

// ---------------- kernel 0: W -> W^T bf16 ----------------
__global__ void wtrans_kernel(const float* __restrict__ Wq, const float* __restrict__ Wk,
                              const float* __restrict__ Wv, unsigned short* __restrict__ Wt){
  const float* src = blockIdx.x == 0 ? Wq : (blockIdx.x == 1 ? Wk : Wv);
  unsigned short* dst = Wt + blockIdx.x * (D_*D_);
  const int i = blockIdx.y * 256 + threadIdx.x;
  const int k = i >> 7, n = i & 127;
  dst[n*D_ + k] = f2bf(src[i]);
}

// ---------------- kernel 1: QKV projection, single-which blocks ----------------
// Rounds 2-5 post-mortem: the 3-which serial chain (MFMA -> store-drain barrier
// -> B-DMA -> DMA-drain barrier, x3) pinned every fused variant at 57-62 us
// with all pipes <30% busy. This version: grid (3, M/64) = 6144 blocks, each
// block does ONE which: issue B DMA -> load A global->reg (hides DMA) ->
// ONE barrier -> ds_read+MFMA -> direct stores -> end. No mid-kernel drains;
// overlap comes from 24 blocks/CU of work with short independent chains.
// B through LDS (broadcast; round-4 showed global-B = gather storm), A direct
// to registers (private operand; round-5 showed this path works).
__global__ __launch_bounds__(256, 2) void qkv_gemm_kernel(
    const float* __restrict__ x, const unsigned short* __restrict__ Wt,
    const float* __restrict__ bq, const float* __restrict__ bk, const float* __restrict__ bv,
    unsigned short* __restrict__ Q, unsigned short* __restrict__ K, unsigned short* __restrict__ V)
{
  const int which = blockIdx.x;          // 0=Q 1=K 2=V
  const int rowTile = blockIdx.y;        // 64-row tile

  __shared__ unsigned short lds[16384];  // B only: 128x128 bf16 = 32 KB

  const int t = threadIdx.x;
  const int wave = t >> 6, lane = t & 63;
  const int m0 = lane & 15, quad = lane >> 4;
  const int wm = (wave >> 1) * 32, wn = (wave & 1) * 64;  // wave -> 32x64 quadrant

  // ---- issue B DMA first; it flies under the A load+convert phase
  {
    const unsigned short* Wsel = Wt + which * (D_*D_);
    #pragma unroll
    for (int p = 0; p < 8; ++p){
      int s = p*256 + t;                 // 16B chunk id
      int n = s >> 4, cp = s & 15, c = cp ^ (n & 7);
      __builtin_amdgcn_global_load_lds((gas_t)(const void*)(Wsel + n*128 + c*8),
                                       (las_t)(void*)((unsigned short*)lds + p*2048 + wave*512),
                                       16, 0, 0);
    }
  }

  // ---- A fragments: global fp32 -> bf16 regs (batched loads, then convert)
  //      a[kk][i]: row = wm + i*16 + m0, k = kk*32 + quad*8 + e
  short8 a[4][2];
  {
    const float* xbase = x + (size_t)(rowTile*64 + wm + m0) * D_ + quad*8;
    float4 f[8][2];
    #pragma unroll
    for (int kk = 0; kk < 4; ++kk)
      #pragma unroll
      for (int i = 0; i < 2; ++i){
        const float* gp = xbase + i*16*D_ + kk*32;
        f[kk*2+i][0] = *(const float4*)gp;
        f[kk*2+i][1] = *(const float4*)(gp + 4);
      }
    #pragma unroll
    for (int kk = 0; kk < 4; ++kk)
      #pragma unroll
      for (int i = 0; i < 2; ++i){
        short8 v;
        v[0] = (short)f2bf(f[kk*2+i][0].x);
        v[1] = (short)f2bf(f[kk*2+i][0].y);
        v[2] = (short)f2bf(f[kk*2+i][0].z);
        v[3] = (short)f2bf(f[kk*2+i][0].w);
        v[4] = (short)f2bf(f[kk*2+i][1].x);
        v[5] = (short)f2bf(f[kk*2+i][1].y);
        v[6] = (short)f2bf(f[kk*2+i][1].z);
        v[7] = (short)f2bf(f[kk*2+i][1].w);
        a[kk][i] = v;
      }
  }
  __syncthreads();   // the ONLY barrier: B landed (vmcnt drained), A in regs

  // acc[j][i] = mfma(b[j], a[kk][i]) -> lane holds C[row=wm+i*16+m0]
  // [col = wn+j*16+quad*4 + r], r=0..3 (consecutive cols -> direct store)
  floatx4 acc[4][2] = {};
  #pragma unroll
  for (int kk = 0; kk < 4; ++kk){
    short8 b[4];
    #pragma unroll
    for (int j = 0; j < 4; ++j){
      int n = wn + j*16 + m0;
      int c = (kk*4 + quad) ^ (n & 7);
      b[j] = *(const short8*)&lds[n*128 + c*8];
    }
    #pragma unroll
    for (int j = 0; j < 4; ++j)
      #pragma unroll
      for (int i = 0; i < 2; ++i)
        acc[j][i] = __builtin_amdgcn_mfma_f32_16x16x32_bf16(b[j], a[kk][i], acc[j][i], 0, 0, 0);
  }

  // ---- epilogue: direct global stores, 8B/lane per (j,i); no drain, just end
  {
    const float* bias = which == 0 ? bq : (which == 1 ? bk : bv);
    unsigned short* Out = which == 0 ? Q : (which == 1 ? K : V);
    unsigned short* Outp = Out + (size_t)rowTile * 64 * D_;
    #pragma unroll
    for (int j = 0; j < 4; ++j){
      const float4 bb = *(const float4*)&bias[wn + j*16 + quad*4];
      #pragma unroll
      for (int i = 0; i < 2; ++i){
        const int row = wm + i*16 + m0;
        uint2 pk;
        pk.x = (unsigned)f2bf(acc[j][i][0] + bb.x) | ((unsigned)f2bf(acc[j][i][1] + bb.y) << 16);
        pk.y = (unsigned)f2bf(acc[j][i][2] + bb.z) | ((unsigned)f2bf(acc[j][i][3] + bb.w) << 16);
        *(uint2*)(Outp + row*D_ + wn + j*16 + quad*4) = pk;
      }
    }
  }
}

// ---------------- kernel 2: 3x3 window attention ----------------
// (unchanged — spill-free batched loads)
__global__ __launch_bounds__(256, 2) void attn_kernel(
    const unsigned short* __restrict__ Q, const unsigned short* __restrict__ K,
    const unsigned short* __restrict__ V, float* __restrict__ out)
{
  const int t = threadIdx.x;
  const int e8 = t & 7;                      // which 16-dim chunk
  const int pix = blockIdx.x * 32 + (t >> 3);
  const int w = pix & 127;
  const int h = (pix >> 7) & 127;
  const int bbase = pix & ~(N_ - 1);         // first pixel of this batch image
  const float scale = 0.08838834764831845f;  // 1/sqrt(128)
  const int doff = e8 * 16;
  const size_t off = (size_t)pix * D_ + doff;

  // ---- neighbor pixel indices, clamped into the image (always valid)
  int npix[9]; bool okm[9];
  #pragma unroll
  for (int i = 0; i < 9; ++i){
    const int dy = i/3 - 1, dx = i%3 - 1;
    const int hh = h + dy, ww = w + dx;
    okm[i] = ((unsigned)hh < 128u) && ((unsigned)ww < 128u);
    const int hc = min(max(hh, 0), 127);
    const int wc = min(max(ww, 0), 127);
    npix[i] = bbase + hc*W_ + wc;
  }

  // ---- issue q, then ALL 9 K, then ALL 9 V (unconditional -> batchable)
  uint4 qu0, qu1;
  {
    const unsigned short* qp = Q + off;
    qu0 = *(const uint4*)qp;
    qu1 = *(const uint4*)(qp + 8);
  }
  uint4 ku[9][2];
  #pragma unroll
  for (int i = 0; i < 9; ++i){
    const unsigned short* kp = K + (size_t)npix[i]*D_ + doff;
    ku[i][0] = *(const uint4*)kp;
    ku[i][1] = *(const uint4*)(kp + 8);
  }
  uint4 vu[9][2];
  #pragma unroll
  for (int i = 0; i < 9; ++i){
    const unsigned short* vp = V + (size_t)npix[i]*D_ + doff;
    vu[i][0] = *(const uint4*)vp;
    vu[i][1] = *(const uint4*)(vp + 8);
  }

  // ---- q unpack + scale
  float q[16];
  {
    unsigned uu[8] = {qu0.x, qu0.y, qu0.z, qu0.w, qu1.x, qu1.y, qu1.z, qu1.w};
    #pragma unroll
    for (int e = 0; e < 8; ++e){
      q[e*2]     = bflo(uu[e]) * scale;
      q[e*2 + 1] = bfhi(uu[e]) * scale;
    }
  }

  // ---- partial dot products (16 dims); OOB -> exact 0 via scalar select
  float s[9];
  #pragma unroll
  for (int i = 0; i < 9; ++i){
    unsigned uu[8] = {ku[i][0].x, ku[i][0].y, ku[i][0].z, ku[i][0].w,
                      ku[i][1].x, ku[i][1].y, ku[i][1].z, ku[i][1].w};
    float acc = 0.f;
    #pragma unroll
    for (int e = 0; e < 8; ++e){
      acc += q[e*2]     * bflo(uu[e]);
      acc += q[e*2 + 1] * bfhi(uu[e]);
    }
    s[i] = okm[i] ? acc : 0.f;
  }
  // 8-lane reduce (all 8 lanes of a pixel share okm, so select-then-reduce ok)
  #pragma unroll
  for (int i = 0; i < 9; ++i){
    s[i] += __shfl_xor(s[i], 1, 64);
    s[i] += __shfl_xor(s[i], 2, 64);
    s[i] += __shfl_xor(s[i], 4, 64);
  }

  // ---- softmax (OOB score is exactly 0, participates — ref zero-pad semantics)
  float m = s[0];
  #pragma unroll
  for (int i = 1; i < 9; ++i) m = fmaxf(m, s[i]);
  float p[9]; float l = 0.f;
  #pragma unroll
  for (int i = 0; i < 9; ++i){ p[i] = __expf(s[i] - m); l += p[i]; }
  const float inv = 1.f / l;

  // ---- PV accumulate; OOB contributes 0 via select on pi
  float o[16];
  #pragma unroll
  for (int d = 0; d < 16; ++d) o[d] = 0.f;
  #pragma unroll
  for (int i = 0; i < 9; ++i){
    const float pi = okm[i] ? p[i] * inv : 0.f;
    unsigned uu[8] = {vu[i][0].x, vu[i][0].y, vu[i][0].z, vu[i][0].w,
                      vu[i][1].x, vu[i][1].y, vu[i][1].z, vu[i][1].w};
    #pragma unroll
    for (int e = 0; e < 8; ++e){
      o[e*2]     += pi * bflo(uu[e]);
      o[e*2 + 1] += pi * bfhi(uu[e]);
    }
  }

  float* op = out + off;
  #pragma unroll
  for (int c = 0; c < 4; ++c){
    float4 v4 = make_float4(o[c*4], o[c*4+1], o[c*4+2], o[c*4+3]);
    *(float4*)(op + c*4) = v4;
  }
}

extern "C" void kernel_launch(void* const* d_in, const int* in_sizes, int n_in,
                              void* d_out, int out_size, void* d_ws, size_t ws_size,
                              hipStream_t stream)
{
  const float* x  = (const float*)d_in[0];
  const float* Wq = (const float*)d_in[1];
  const float* bq = (const float*)d_in[2];
  const float* Wk = (const float*)d_in[3];
  const float* bk = (const float*)d_in[4];
  const float* Wv = (const float*)d_in[5];
  const float* bv = (const float*)d_in[6];
  float* out = (float*)d_out;

  char* ws = (char*)d_ws;
  unsigned short* Wt = (unsigned short*)ws;                                   // 96 KB
  unsigned short* Q  = (unsigned short*)(ws + (1<<17));
  unsigned short* K  = (unsigned short*)(ws + (1<<17) + (size_t)M_*D_*2);
  unsigned short* V  = (unsigned short*)(ws + (1<<17) + (size_t)2*M_*D_*2);   // ~96.1 MB

  hipLaunchKernelGGL(wtrans_kernel, dim3(3, 64), dim3(256), 0, stream, Wq, Wk, Wv, Wt);
  hipLaunchKernelGGL(qkv_gemm_kernel, dim3(3, M_/64), dim3(256), 0, stream,
                     x, Wt, bq, bk, bv, Q, K, V);
  hipLaunchKernelGGL(attn_kernel, dim3(M_/32), dim3(256), 0, stream, Q, K, V, out);
}

// Round 7
// 202.324 us; speedup vs baseline: 1.1317x; 1.1317x over previous
//
#include <hip/hip_runtime.h>
#include <stdint.h>

#define B_ 8
#define H_ 128
#define W_ 128
#define D_ 128
#define N_ (H_*W_)
#define M_ (B_*N_)   // 131072 rows total

typedef __attribute__((ext_vector_type(8))) short short8;
typedef __attribute__((ext_vector_type(4))) float floatx4;

typedef const __attribute__((address_space(1))) void* gas_t;
typedef __attribute__((address_space(3))) void* las_t;

__device__ inline unsigned short f2bf(float f){
  union { float f; unsigned int i; } c; c.f = f;
  unsigned int x = c.i;
  x += 0x7FFF + ((x >> 16) & 1);   // RNE
  return (unsigned short)(x >> 16);
}
__device__ inline float bflo(unsigned int u){
  union { unsigned int i; float f; } c; c.i = u << 16; return c.f;
}
__device__ inline float bfhi(unsigned int u){
  union { unsigned int i; float f; } c; c.i = u & 0xFFFF0000u; return c.f;
}

// ---------------- kernel 0: W -> W^T bf16 ----------------
__global__ void wtrans_kernel(const float* __restrict__ Wq, const float* __restrict__ Wk,
                              const float* __restrict__ Wv, unsigned short* __restrict__ Wt){
  const float* src = blockIdx.x == 0 ? Wq : (blockIdx.x == 1 ? Wk : Wv);
  unsigned short* dst = Wt + blockIdx.x * (D_*D_);
  const int i = blockIdx.y * 256 + threadIdx.x;
  const int k = i >> 7, n = i & 127;
  dst[n*D_ + k] = f2bf(src[i]);
}

__device__ __forceinline__ void stage_B(unsigned short* ldsbase, const unsigned short* Wsel,
                                        int t, int wave){
  #pragma unroll
  for (int p = 0; p < 8; ++p){
    int s = p*256 + t, n = s >> 4, cp = s & 15, c = cp ^ (n & 7);
    __builtin_amdgcn_global_load_lds((gas_t)(const void*)(Wsel + n*128 + c*8),
                                     (las_t)(void*)(ldsbase + p*2048 + wave*512), 16, 0, 0);
  }
}

// ---------------- kernel 1: FUSED QKV, counted-vmcnt double-buffer ----------------
// Rounds 2-5: every fused variant pinned at 57-62 us; the invariant was
// __syncthreads' full vmcnt(0) drain between which-phases (3x per block, 2
// blocks/CU to cover). This version: raw s_barrier + counted s_waitcnt vmcnt(N)
// (T3/T4 pattern) so prefetch DMAs stay in flight across barriers. Per-thread
// vm-op FIFO: B0(8), A(32), B1(8), st0(16), B2(8), st1(16) -> waits vmcnt(8)/
// vmcnt(24)/vmcnt(16) guarantee the needed buffer landed, never drain younger
// prefetch/stores. A-loads batched with sched_barrier(0) (rounds 4/6: compiler
// otherwise serializes them at VGPR~52). x read once (round 6: un-fusing
// tripled FETCH). B via LDS DMA (round 4: global-B = gather storm).
__global__ __launch_bounds__(256, 2) void qkv_gemm_kernel(
    const float* __restrict__ x, const unsigned short* __restrict__ Wt,
    const float* __restrict__ bq, const float* __restrict__ bk, const float* __restrict__ bv,
    unsigned short* __restrict__ Q, unsigned short* __restrict__ K, unsigned short* __restrict__ V)
{
  const int rowTile = blockIdx.x;

  __shared__ unsigned short lds[32768];  // buf0 [0,16384), buf1 [16384,32768) = 64 KB

  const int t = threadIdx.x;
  const int wave = t >> 6, lane = t & 63;
  const int m0 = lane & 15, quad = lane >> 4;
  const int wm = (wave >> 1) * 64, wn = (wave & 1) * 64;  // wave -> 64x64 quadrant

  // ---- issue B0 DMA (8 vm-ops) — flies under the A load+convert phase
  stage_B((unsigned short*)lds, Wt, t, wave);

  // ---- A fragments: global fp32 -> bf16 regs, two half-passes of 16 batched
  //      loads each. a[kk][i]: row = wm + i*16 + m0, k = kk*32 + quad*8 + e.
  short8 a[4][4];
  const float* xbase = x + (size_t)(rowTile*128 + wm + m0) * D_ + quad*8;
  #pragma unroll
  for (int half = 0; half < 2; ++half){
    float4 f[8][2];
    #pragma unroll
    for (int kk2 = 0; kk2 < 2; ++kk2)
      #pragma unroll
      for (int i = 0; i < 4; ++i){
        const float* gp = xbase + i*16*D_ + (half*2 + kk2)*32;
        f[kk2*4+i][0] = *(const float4*)gp;
        f[kk2*4+i][1] = *(const float4*)(gp + 4);
      }
    __builtin_amdgcn_sched_barrier(0);   // keep the 16 loads batched before converts
    #pragma unroll
    for (int kk2 = 0; kk2 < 2; ++kk2)
      #pragma unroll
      for (int i = 0; i < 4; ++i){
        short8 v;
        v[0] = (short)f2bf(f[kk2*4+i][0].x);
        v[1] = (short)f2bf(f[kk2*4+i][0].y);
        v[2] = (short)f2bf(f[kk2*4+i][0].z);
        v[3] = (short)f2bf(f[kk2*4+i][0].w);
        v[4] = (short)f2bf(f[kk2*4+i][1].x);
        v[5] = (short)f2bf(f[kk2*4+i][1].y);
        v[6] = (short)f2bf(f[kk2*4+i][1].z);
        v[7] = (short)f2bf(f[kk2*4+i][1].w);
        a[half*2 + kk2][i] = v;
      }
  }

  // ---- issue B1 DMA (8 vm-ops) into buf1; do NOT wait for it
  stage_B((unsigned short*)lds + 16384, Wt + D_*D_, t, wave);

  // B0 + A retired when <=8 outstanding (B1 is the youngest 8). No full drain.
  asm volatile("s_waitcnt vmcnt(8)" ::: "memory");
  __builtin_amdgcn_sched_barrier(0);
  __builtin_amdgcn_s_barrier();          // buf0 valid for all waves

  #pragma unroll
  for (int which = 0; which < 3; ++which){
    const int bufbase = (which & 1) ? 16384 : 0;

    // acc[j][i] = mfma(b[j], a[kk][i]) -> lane holds C[row=wm+i*16+m0]
    // [col = wn+j*16+quad*4 + r], r=0..3 (consecutive cols -> direct store)
    floatx4 acc[4][4] = {};
    #pragma unroll
    for (int kk = 0; kk < 4; ++kk){
      short8 b[4];
      #pragma unroll
      for (int j = 0; j < 4; ++j){
        int n = wn + j*16 + m0;
        int c = (kk*4 + quad) ^ (n & 7);
        b[j] = *(const short8*)&lds[bufbase + n*128 + c*8];
      }
      #pragma unroll
      for (int j = 0; j < 4; ++j)
        #pragma unroll
        for (int i = 0; i < 4; ++i)
          acc[j][i] = __builtin_amdgcn_mfma_f32_16x16x32_bf16(b[j], a[kk][i], acc[j][i], 0, 0, 0);
    }

    // ---- epilogue: direct global stores (16 uint2 vm-ops per thread)
    {
      const float* bias = which == 0 ? bq : (which == 1 ? bk : bv);
      unsigned short* Out = which == 0 ? Q : (which == 1 ? K : V);
      unsigned short* Outp = Out + (size_t)rowTile * 128 * D_;
      #pragma unroll
      for (int j = 0; j < 4; ++j){
        const float4 bb = *(const float4*)&bias[wn + j*16 + quad*4];
        #pragma unroll
        for (int i = 0; i < 4; ++i){
          const int row = wm + i*16 + m0;
          uint2 pk;
          pk.x = (unsigned)f2bf(acc[j][i][0] + bb.x) | ((unsigned)f2bf(acc[j][i][1] + bb.y) << 16);
          pk.y = (unsigned)f2bf(acc[j][i][2] + bb.z) | ((unsigned)f2bf(acc[j][i][3] + bb.w) << 16);
          *(uint2*)(Outp + row*D_ + wn + j*16 + quad*4) = pk;
        }
      }
    }

    if (which == 0){
      __builtin_amdgcn_s_barrier();            // all waves done READING buf0
      stage_B((unsigned short*)lds, Wt + 2*(D_*D_), t, wave);   // B2 -> buf0
      // FIFO outstanding <= B1(8)+st0(16)+B2(8)=32; vmcnt(24) -> B1 retired.
      asm volatile("s_waitcnt vmcnt(24)" ::: "memory");
      __builtin_amdgcn_sched_barrier(0);
      __builtin_amdgcn_s_barrier();            // buf1 valid
    } else if (which == 1){
      // outstanding <= st0(16)+B2(8)+st1(16)=40; vmcnt(16) -> B2 retired
      // (only st1, the youngest 16, may remain in flight).
      asm volatile("s_waitcnt vmcnt(16)" ::: "memory");
      __builtin_amdgcn_sched_barrier(0);
      __builtin_amdgcn_s_barrier();            // buf0 (B2) valid
    }
  }
}

// ---------------- kernel 2: 3x3 window attention ----------------
// (unchanged — spill-free batched loads)
__global__ __launch_bounds__(256, 2) void attn_kernel(
    const unsigned short* __restrict__ Q, const unsigned short* __restrict__ K,
    const unsigned short* __restrict__ V, float* __restrict__ out)
{
  const int t = threadIdx.x;
  const int e8 = t & 7;                      // which 16-dim chunk
  const int pix = blockIdx.x * 32 + (t >> 3);
  const int w = pix & 127;
  const int h = (pix >> 7) & 127;
  const int bbase = pix & ~(N_ - 1);         // first pixel of this batch image
  const float scale = 0.08838834764831845f;  // 1/sqrt(128)
  const int doff = e8 * 16;
  const size_t off = (size_t)pix * D_ + doff;

  // ---- neighbor pixel indices, clamped into the image (always valid)
  int npix[9]; bool okm[9];
  #pragma unroll
  for (int i = 0; i < 9; ++i){
    const int dy = i/3 - 1, dx = i%3 - 1;
    const int hh = h + dy, ww = w + dx;
    okm[i] = ((unsigned)hh < 128u) && ((unsigned)ww < 128u);
    const int hc = min(max(hh, 0), 127);
    const int wc = min(max(ww, 0), 127);
    npix[i] = bbase + hc*W_ + wc;
  }

  // ---- issue q, then ALL 9 K, then ALL 9 V (unconditional -> batchable)
  uint4 qu0, qu1;
  {
    const unsigned short* qp = Q + off;
    qu0 = *(const uint4*)qp;
    qu1 = *(const uint4*)(qp + 8);
  }
  uint4 ku[9][2];
  #pragma unroll
  for (int i = 0; i < 9; ++i){
    const unsigned short* kp = K + (size_t)npix[i]*D_ + doff;
    ku[i][0] = *(const uint4*)kp;
    ku[i][1] = *(const uint4*)(kp + 8);
  }
  uint4 vu[9][2];
  #pragma unroll
  for (int i = 0; i < 9; ++i){
    const unsigned short* vp = V + (size_t)npix[i]*D_ + doff;
    vu[i][0] = *(const uint4*)vp;
    vu[i][1] = *(const uint4*)(vp + 8);
  }

  // ---- q unpack + scale
  float q[16];
  {
    unsigned uu[8] = {qu0.x, qu0.y, qu0.z, qu0.w, qu1.x, qu1.y, qu1.z, qu1.w};
    #pragma unroll
    for (int e = 0; e < 8; ++e){
      q[e*2]     = bflo(uu[e]) * scale;
      q[e*2 + 1] = bfhi(uu[e]) * scale;
    }
  }

  // ---- partial dot products (16 dims); OOB -> exact 0 via scalar select
  float s[9];
  #pragma unroll
  for (int i = 0; i < 9; ++i){
    unsigned uu[8] = {ku[i][0].x, ku[i][0].y, ku[i][0].z, ku[i][0].w,
                      ku[i][1].x, ku[i][1].y, ku[i][1].z, ku[i][1].w};
    float acc = 0.f;
    #pragma unroll
    for (int e = 0; e < 8; ++e){
      acc += q[e*2]     * bflo(uu[e]);
      acc += q[e*2 + 1] * bfhi(uu[e]);
    }
    s[i] = okm[i] ? acc : 0.f;
  }
  // 8-lane reduce (all 8 lanes of a pixel share okm, so select-then-reduce ok)
  #pragma unroll
  for (int i = 0; i < 9; ++i){
    s[i] += __shfl_xor(s[i], 1, 64);
    s[i] += __shfl_xor(s[i], 2, 64);
    s[i] += __shfl_xor(s[i], 4, 64);
  }

  // ---- softmax (OOB score is exactly 0, participates — ref zero-pad semantics)
  float m = s[0];
  #pragma unroll
  for (int i = 1; i < 9; ++i) m = fmaxf(m, s[i]);
  float p[9]; float l = 0.f;
  #pragma unroll
  for (int i = 0; i < 9; ++i){ p[i] = __expf(s[i] - m); l += p[i]; }
  const float inv = 1.f / l;

  // ---- PV accumulate; OOB contributes 0 via select on pi
  float o[16];
  #pragma unroll
  for (int d = 0; d < 16; ++d) o[d] = 0.f;
  #pragma unroll
  for (int i = 0; i < 9; ++i){
    const float pi = okm[i] ? p[i] * inv : 0.f;
    unsigned uu[8] = {vu[i][0].x, vu[i][0].y, vu[i][0].z, vu[i][0].w,
                      vu[i][1].x, vu[i][1].y, vu[i][1].z, vu[i][1].w};
    #pragma unroll
    for (int e = 0; e < 8; ++e){
      o[e*2]     += pi * bflo(uu[e]);
      o[e*2 + 1] += pi * bfhi(uu[e]);
    }
  }

  float* op = out + off;
  #pragma unroll
  for (int c = 0; c < 4; ++c){
    float4 v4 = make_float4(o[c*4], o[c*4+1], o[c*4+2], o[c*4+3]);
    *(float4*)(op + c*4) = v4;
  }
}

extern "C" void kernel_launch(void* const* d_in, const int* in_sizes, int n_in,
                              void* d_out, int out_size, void* d_ws, size_t ws_size,
                              hipStream_t stream)
{
  const float* x  = (const float*)d_in[0];
  const float* Wq = (const float*)d_in[1];
  const float* bq = (const float*)d_in[2];
  const float* Wk = (const float*)d_in[3];
  const float* bk = (const float*)d_in[4];
  const float* Wv = (const float*)d_in[5];
  const float* bv = (const float*)d_in[6];
  float* out = (float*)d_out;

  char* ws = (char*)d_ws;
  unsigned short* Wt = (unsigned short*)ws;                                   // 96 KB
  unsigned short* Q  = (unsigned short*)(ws + (1<<17));
  unsigned short* K  = (unsigned short*)(ws + (1<<17) + (size_t)M_*D_*2);
  unsigned short* V  = (unsigned short*)(ws + (1<<17) + (size_t)2*M_*D_*2);   // ~96.1 MB

  hipLaunchKernelGGL(wtrans_kernel, dim3(3, 64), dim3(256), 0, stream, Wq, Wk, Wv, Wt);
  hipLaunchKernelGGL(qkv_gemm_kernel, dim3(M_/128), dim3(256), 0, stream,
                     x, Wt, bq, bk, bv, Q, K, V);
  hipLaunchKernelGGL(attn_kernel, dim3(M_/32), dim3(256), 0, stream, Q, K, V, out);
}